// Round 15
// baseline (109.692 us; speedup 1.0000x reference)
//
#include <hip/hip_runtime.h>
#include <math.h>

// DeformConv2dPack on MI355X (gfx950) — v15
// B=8, C=256, H=W=64, Cout=256, K=3x3, stride=1, pad=1, dil=1
//
// v15 = v14 with the fused offset-conv prologue rebuilt barrier-free:
//  B-fragments loaded DIRECTLY from NHWC xt (lane (l16,lh) reads the 16B of
//  channels cc*64+kk*32+lh*8 for pixel nf*16+l16 — contiguous 64B per pixel
//  across the 4 lh lanes), A from womp. 72 independent load+MFMA per wave,
//  ZERO barriers / ZERO LDS staging (v14's prologue paid 36 syncthreads and
//  294KB LDS round-trip for 1/16 the MFMA work). Two accumulators (kk=0/1)
//  halve the MFMA dependency chain. 2x B redundancy across mf-paired waves
//  is ~4us of L2 traffic chip-wide vs ~15us of barrier wall removed.
//  Main loop, samp precompute, prep: unchanged from v14 (proven).
//
// ws layout:
//  [0)          xt bf16 NHWC   16,777,216 B
//  [16777216)   Wpack bf16      1,179,648 B
//  [17956864)   Womp bf16         147,456 B   (end 18,104,320)

typedef __bf16 bf16x8 __attribute__((ext_vector_type(8)));
typedef float  f32x4  __attribute__((ext_vector_type(4)));
typedef float  f32x2  __attribute__((ext_vector_type(2)));
typedef int    i32x4  __attribute__((ext_vector_type(4)));
typedef unsigned short u16x8 __attribute__((ext_vector_type(8)));
typedef unsigned short u16x4 __attribute__((ext_vector_type(4)));

__device__ __forceinline__ unsigned short f2b(float f) {
  return __builtin_bit_cast(unsigned short, (__bf16)f);
}
__device__ __forceinline__ float blo(unsigned u) {
  return __builtin_bit_cast(float, u << 16);
}
__device__ __forceinline__ float bhi(unsigned u) {
  return __builtin_bit_cast(float, u & 0xffff0000u);
}

// prep: blocks [0,2048) transpose x NCHW->NHWC bf16; [2048,4352) pack main
// weight; [4352,4640) pack offset/mask weights.
__global__ __launch_bounds__(256) void prep(const float* __restrict__ x,
                                            unsigned short* __restrict__ xt,
                                            const float* __restrict__ w,
                                            const float* __restrict__ wo,
                                            const float* __restrict__ wm,
                                            __bf16* __restrict__ wp,
                                            __bf16* __restrict__ womp) {
  __shared__ float tile[64][65];
  const int t = threadIdx.x;
  if (blockIdx.x < 2048) {
    const int bid = blockIdx.x;
    const int b = bid & 7, rem = bid >> 3;
    const int cc = rem & 3, hw0 = (rem >> 2) << 6;
    const int a = t & 63, g = t >> 6;
#pragma unroll
    for (int r = 0; r < 16; ++r) {
      int crow = (r << 2) + g;
      tile[crow][a] = x[(((b << 8) + (cc << 6) + crow) << 12) + hw0 + a];
    }
    __syncthreads();
    const int a0 = (t & 15) << 2, gg = t >> 4;
#pragma unroll
    for (int r = 0; r < 4; ++r) {
      int hwr = (r << 4) + gg;
      u16x4 v;
#pragma unroll
      for (int j = 0; j < 4; ++j) v[j] = f2b(tile[a0 + j][hwr]);
      *(u16x4*)&xt[((b << 12) + hw0 + hwr) * 256 + (cc << 6) + a0] = v;
    }
  } else if (blockIdx.x < 4352) {
    int idx = (blockIdx.x - 2048) * 256 + t;
    int o = idx / 2304, rem = idx - o * 2304;
    int c = rem / 9, k = rem - c * 9;
    wp[(((k << 5) + (c >> 3)) * 256 + o) * 8 + (c & 7)] = (__bf16)w[idx];
  } else {
    int idx = (blockIdx.x - 4352) * 256 + t;
    if (idx >= 32 * 256 * 9) return;
    int r = idx / 2304, rem = idx - r * 2304;
    int c = rem / 9, k = rem - c * 9;
    float v = 0.f;
    if (r < 18) v = wo[((r << 8) + c) * 9 + k];
    else if (r < 27) v = wm[(((r - 18) << 8) + c) * 9 + k];
    womp[(((k << 5) + (c >> 3)) * 32 + r) * 8 + (c & 7)] = (__bf16)v;
  }
}

// deform_fused: grid = 512 (bi = bid&7 XCD, h = bid>>3), 512 threads (8 waves).
// Prologue: barrier-free offset/mask conv (direct global B loads) -> offm LDS.
// Main: v13 deformable GEMM, S XOR-swizzled, __syncthreads barriers.
__global__ __launch_bounds__(512, 2) void deform_fused(
    const unsigned short* __restrict__ xt, const __bf16* __restrict__ wp,
    const __bf16* __restrict__ womp, const float* __restrict__ b_off,
    const float* __restrict__ b_msk, const float* __restrict__ bias,
    float* __restrict__ out) {
  const int bi = blockIdx.x & 7, h = blockIdx.x >> 3;
  const int t = threadIdx.x, lane = t & 63, wv = t >> 6;
  const int l16 = lane & 15, lh = lane >> 4;
  __shared__ __align__(16) unsigned short S[2][64 * 64];  // 16 KB, swizzled
  __shared__ __align__(16) float samp[9][64][8];          // 18 KB
  __shared__ __align__(16) float offm[27][64];            // 6.75 KB

  const int sp = t >> 3;                  // staging pixel row, 8 thr/px
  const int sc0 = (t & 7) << 3;           // 8 ch each (granule g = t&7)
  const int wofs = (sp << 6) + ((((t & 7) ^ (sp & 7)) & 7) << 3);  // swizzled
  const unsigned short* xtb = xt + ((long)bi << 20);

  // ---- Prologue: offset/mask conv, barrier-free direct-load GEMM ----
  {
    f32x4 oacc0 = {}, oacc1 = {};
    const int mf = wv & 1, nf = wv >> 1;
    const int px = (nf << 4) + l16;
    const int chl = lh << 3;  // lane channel offset within chunk

#pragma unroll
    for (int k = 0; k < 9; ++k) {
      const int hh = h + k / 3 - 1;
      const int ww = px + (k % 3) - 1;
      const bool valid = (hh >= 0) & (hh < 64) & (ww >= 0) & (ww < 64);
      const unsigned short* base = xtb + (((hh << 6) + ww) << 8) + chl;
#pragma unroll
      for (int cc = 0; cc < 4; ++cc) {
        bf16x8 bf0 = bf16x8{}, bf1 = bf16x8{};
        if (valid) {
          bf0 = *(const bf16x8*)(base + (cc << 6));
          bf1 = *(const bf16x8*)(base + (cc << 6) + 32);
        }
        const __bf16* ap0 = womp + ((((k << 5) + (cc << 3) + lh) << 5) + (mf << 4) + l16) * 8;
        bf16x8 af0 = *(const bf16x8*)ap0;
        bf16x8 af1 = *(const bf16x8*)(ap0 + (4 << 5) * 8);  // kk=1: +4 rows of 32*8
        oacc0 = __builtin_amdgcn_mfma_f32_16x16x32_bf16(af0, bf0, oacc0, 0, 0, 0);
        oacc1 = __builtin_amdgcn_mfma_f32_16x16x32_bf16(af1, bf1, oacc1, 0, 0, 0);
      }
    }
    f32x4 oacc = oacc0 + oacc1;

#pragma unroll
    for (int r = 0; r < 4; ++r) {
      int row = (mf << 4) + (lh << 2) + r;
      if (row < 18) {
        offm[row][px] = oacc[r] + b_off[row];
      } else if (row < 27) {
        float v = oacc[r] + b_msk[row - 18];
        offm[row][px] = 1.f / (1.f + expf(-v));
      }
    }
    __syncthreads();
  }

  // ---- Precompute per-(tap,px) interp weights + clamped corner offsets ----
  for (int i = t; i < 576; i += 512) {
    int k = i >> 6, p = i & 63;
    float dy = offm[(k << 1)][p], dx = offm[(k << 1) + 1][p], mk = offm[18 + k][p];
    float ys = (float)(h + k / 3 - 1) + dy;
    float xs = (float)(p + k % 3 - 1) + dx;
    float y0f = floorf(ys), x0f = floorf(xs);
    int iy0 = (int)y0f, ix0 = (int)x0f;
    float wy1 = ys - y0f, wx1 = xs - x0f;
    float wy0 = 1.f - wy1, wx0 = 1.f - wx1;
    float w00 = wy0 * wx0 * mk, w01 = wy0 * wx1 * mk;
    float w10 = wy1 * wx0 * mk, w11 = wy1 * wx1 * mk;
    if (iy0 < 0 || iy0 > 63) { w00 = 0.f; w01 = 0.f; }
    if (iy0 < -1 || iy0 > 62) { w10 = 0.f; w11 = 0.f; }
    if (ix0 < 0 || ix0 > 63) { w00 = 0.f; w10 = 0.f; }
    if (ix0 < -1 || ix0 > 62) { w01 = 0.f; w11 = 0.f; }
    const int cy0 = min(max(iy0, 0), 63), cy1 = min(max(iy0 + 1, 0), 63);
    const int cx0 = min(max(ix0, 0), 63), cx1 = min(max(ix0 + 1, 0), 63);
    samp[k][p][0] = w00; samp[k][p][1] = w01;
    samp[k][p][2] = w10; samp[k][p][3] = w11;
    samp[k][p][4] = __builtin_bit_cast(float, (((cy0 << 6) + cx0) << 8));
    samp[k][p][5] = __builtin_bit_cast(float, (((cy0 << 6) + cx1) << 8));
    samp[k][p][6] = __builtin_bit_cast(float, (((cy1 << 6) + cx0) << 8));
    samp[k][p][7] = __builtin_bit_cast(float, (((cy1 << 6) + cx1) << 8));
  }
  __syncthreads();

  // ---- Main deformable GEMM (unchanged from v13) ----
  f32x4 acc[2][4] = {};

  auto GATHER = [&](int it, u16x8* r, f32x4& w4) {
    const int k = it >> 2, cc = it & 3;
    w4 = *(const f32x4*)&samp[k][sp][0];
    i32x4 o4 = __builtin_bit_cast(i32x4, *(const f32x4*)&samp[k][sp][4]);
    const int c0 = (cc << 6) + sc0;
    r[0] = *(const u16x8*)(xtb + o4.x + c0);
    r[1] = *(const u16x8*)(xtb + o4.y + c0);
    r[2] = *(const u16x8*)(xtb + o4.z + c0);
    r[3] = *(const u16x8*)(xtb + o4.w + c0);
  };

  auto STEP = [&](int it, const u16x8* r, const f32x4& w4, int buf) {
    u16x8 sv;
    const unsigned* u0 = (const unsigned*)&r[0];
    const unsigned* u1 = (const unsigned*)&r[1];
    const unsigned* u2 = (const unsigned*)&r[2];
    const unsigned* u3 = (const unsigned*)&r[3];
#pragma unroll
    for (int j = 0; j < 4; ++j) {
      f32x2 a{blo(u0[j]), bhi(u0[j])};
      f32x2 b{blo(u1[j]), bhi(u1[j])};
      f32x2 c{blo(u2[j]), bhi(u2[j])};
      f32x2 d{blo(u3[j]), bhi(u3[j])};
      f32x2 s = a * w4.x;
      s += b * w4.y;
      s += c * w4.z;
      s += d * w4.w;
      sv[2 * j]     = f2b(s.x);
      sv[2 * j + 1] = f2b(s.y);
    }
    *(u16x8*)&S[buf][wofs] = sv;
    __syncthreads();
    const int k = it >> 2, cc = it & 3;
#pragma unroll
    for (int kk = 0; kk < 2; ++kk) {
      bf16x8 bfr[4];
#pragma unroll
      for (int nf = 0; nf < 4; ++nf) {
        const int prow = (nf << 4) + l16;
        const int gi = (kk << 2) | lh;
        bfr[nf] = *(const bf16x8*)&S[buf][(prow << 6) + (((gi ^ (prow & 7)) & 7) << 3)];
      }
#pragma unroll
      for (int mf = 0; mf < 2; ++mf) {
        const int orow = (wv << 5) + (mf << 4) + l16;
        const __bf16* ap = wp + ((((k << 5) + (cc << 3) + (kk << 2) + lh) << 8) + orow) * 8;
        bf16x8 af = *(const bf16x8*)ap;
#pragma unroll
        for (int nf = 0; nf < 4; ++nf)
          acc[mf][nf] = __builtin_amdgcn_mfma_f32_16x16x32_bf16(af, bfr[nf], acc[mf][nf], 0, 0, 0);
      }
    }
  };

  u16x8 rA[4], rB[4];
  f32x4 wA, wB;
  GATHER(0, rA, wA);
  for (int it = 0; it < 36; it += 2) {
    GATHER(it + 1, rB, wB);
    STEP(it, rA, wA, 0);
    if (it + 2 < 36) GATHER(it + 2, rA, wA);
    STEP(it + 1, rB, wB, 1);
  }

#pragma unroll
  for (int mf = 0; mf < 2; ++mf) {
    const int o = (wv << 5) + (mf << 4) + (lh << 2);
    f32x4 bv = *(const f32x4*)(bias + o);
#pragma unroll
    for (int nf = 0; nf < 4; ++nf) {
      const int p = (nf << 4) + l16;
      const int hw = (h << 6) + p;
#pragma unroll
      for (int r = 0; r < 4; ++r)
        out[(((bi << 8) + o + r) << 12) + hw] = acc[mf][nf][r] + bv[r];
    }
  }
}

extern "C" void kernel_launch(void* const* d_in, const int* in_sizes, int n_in,
                              void* d_out, int out_size, void* d_ws, size_t ws_size,
                              hipStream_t stream) {
  (void)in_sizes; (void)n_in; (void)out_size; (void)ws_size;
  const float* x        = (const float*)d_in[0];
  const float* w_offset = (const float*)d_in[1];
  const float* b_offset = (const float*)d_in[2];
  const float* w_mask   = (const float*)d_in[3];
  const float* b_mask   = (const float*)d_in[4];
  const float* weight   = (const float*)d_in[5];
  const float* bias     = (const float*)d_in[6];
  float* out = (float*)d_out;

  char* ws = (char*)d_ws;
  unsigned short* xt = (unsigned short*)(ws);
  __bf16* Wpack  = (__bf16*)(ws + 16777216);
  __bf16* Womp   = (__bf16*)(ws + 17956864);

  prep<<<4640, 256, 0, stream>>>(x, xt, weight, w_offset, w_mask, Wpack, Womp);
  deform_fused<<<512, 512, 0, stream>>>(xt, Wpack, Womp, b_offset, b_mask, bias, out);
}

// Round 16
// 85.906 us; speedup vs baseline: 1.2769x; 1.2769x over previous
//
#include <hip/hip_runtime.h>
#include <math.h>

// DeformConv2dPack on MI355X (gfx950) — v16
// B=8, C=256, H=W=64, Cout=256, K=3x3, stride=1, pad=1, dil=1
//
// v16 = v14 (proven 92.0us total) with the fused offset-conv prologue
//       switched to BK=128 periods: 4 LDS sub-buffers, stage TWO 64-ch chunks
//       per period, ONE __syncthreads, 4 MFMAs -> prologue barriers 36 -> 18.
//       Safe where v11's main-loop BK=128 failed: prologue staging state is
//       2 x u16x8 = 8 transient VGPRs (vs 32 of gather state in the main loop).
//       Loads issue at period start; latency hides under the period's MFMAs.
//       v15's barrier-free prologue (serialized load->MFMA chain) reverted.
//       Main loop / samp / prep byte-identical to v14.
//
// ws layout:
//  [0)          xt bf16 NHWC   16,777,216 B
//  [16777216)   Wpack bf16      1,179,648 B
//  [17956864)   Womp bf16         147,456 B   (end 18,104,320)

typedef __bf16 bf16x8 __attribute__((ext_vector_type(8)));
typedef float  f32x4  __attribute__((ext_vector_type(4)));
typedef float  f32x2  __attribute__((ext_vector_type(2)));
typedef int    i32x4  __attribute__((ext_vector_type(4)));
typedef unsigned short u16x8 __attribute__((ext_vector_type(8)));
typedef unsigned short u16x4 __attribute__((ext_vector_type(4)));

__device__ __forceinline__ unsigned short f2b(float f) {
  return __builtin_bit_cast(unsigned short, (__bf16)f);
}
__device__ __forceinline__ float blo(unsigned u) {
  return __builtin_bit_cast(float, u << 16);
}
__device__ __forceinline__ float bhi(unsigned u) {
  return __builtin_bit_cast(float, u & 0xffff0000u);
}

// prep: blocks [0,2048) transpose x NCHW->NHWC bf16; [2048,4352) pack main
// weight; [4352,4640) pack offset/mask weights.
__global__ __launch_bounds__(256) void prep(const float* __restrict__ x,
                                            unsigned short* __restrict__ xt,
                                            const float* __restrict__ w,
                                            const float* __restrict__ wo,
                                            const float* __restrict__ wm,
                                            __bf16* __restrict__ wp,
                                            __bf16* __restrict__ womp) {
  __shared__ float tile[64][65];
  const int t = threadIdx.x;
  if (blockIdx.x < 2048) {
    const int bid = blockIdx.x;
    const int b = bid & 7, rem = bid >> 3;
    const int cc = rem & 3, hw0 = (rem >> 2) << 6;
    const int a = t & 63, g = t >> 6;
#pragma unroll
    for (int r = 0; r < 16; ++r) {
      int crow = (r << 2) + g;
      tile[crow][a] = x[(((b << 8) + (cc << 6) + crow) << 12) + hw0 + a];
    }
    __syncthreads();
    const int a0 = (t & 15) << 2, gg = t >> 4;
#pragma unroll
    for (int r = 0; r < 4; ++r) {
      int hwr = (r << 4) + gg;
      u16x4 v;
#pragma unroll
      for (int j = 0; j < 4; ++j) v[j] = f2b(tile[a0 + j][hwr]);
      *(u16x4*)&xt[((b << 12) + hw0 + hwr) * 256 + (cc << 6) + a0] = v;
    }
  } else if (blockIdx.x < 4352) {
    int idx = (blockIdx.x - 2048) * 256 + t;
    int o = idx / 2304, rem = idx - o * 2304;
    int c = rem / 9, k = rem - c * 9;
    wp[(((k << 5) + (c >> 3)) * 256 + o) * 8 + (c & 7)] = (__bf16)w[idx];
  } else {
    int idx = (blockIdx.x - 4352) * 256 + t;
    if (idx >= 32 * 256 * 9) return;
    int r = idx / 2304, rem = idx - r * 2304;
    int c = rem / 9, k = rem - c * 9;
    float v = 0.f;
    if (r < 18) v = wo[((r << 8) + c) * 9 + k];
    else if (r < 27) v = wm[(((r - 18) << 8) + c) * 9 + k];
    womp[(((k << 5) + (c >> 3)) * 32 + r) * 8 + (c & 7)] = (__bf16)v;
  }
}

// deform_fused: grid = 512 (bi = bid&7 XCD, h = bid>>3), 512 threads (8 waves).
// Prologue: BK=128 staged offset/mask conv (18 periods, 4 LDS sub-buffers)
//           -> offm[27][64] in LDS. Then samp precompute, then main GEMM.
// S layout per buffer: [row*64 + ((g16 ^ (row&7))<<3)] shorts (XOR swizzle).
__global__ __launch_bounds__(512, 2) void deform_fused(
    const unsigned short* __restrict__ xt, const __bf16* __restrict__ wp,
    const __bf16* __restrict__ womp, const float* __restrict__ b_off,
    const float* __restrict__ b_msk, const float* __restrict__ bias,
    float* __restrict__ out) {
  const int bi = blockIdx.x & 7, h = blockIdx.x >> 3;
  const int t = threadIdx.x, lane = t & 63, wv = t >> 6;
  const int l16 = lane & 15, lh = lane >> 4;
  __shared__ __align__(16) unsigned short S[4][64 * 64];  // 32 KB (main uses [0..1])
  __shared__ __align__(16) float samp[9][64][8];          // 18 KB
  __shared__ __align__(16) float offm[27][64];            // 6.75 KB

  const int sp = t >> 3;                  // staging pixel row, 8 thr/px
  const int sc0 = (t & 7) << 3;           // 8 ch each (granule g = t&7)
  const int wofs = (sp << 6) + ((((t & 7) ^ (sp & 7)) & 7) << 3);  // swizzled
  const unsigned short* xtb = xt + ((long)bi << 20);

  // ---- Prologue: offset/mask conv, BK=128 periods, 18 barriers ----
  {
    f32x4 oacc0 = {}, oacc1 = {};
    const int mf = wv & 1, nf = wv >> 1;

    auto PLOAD = [&](int it, u16x8& r) {
      const int k = it >> 2, cc = it & 3;
      const int hh = h + k / 3 - 1;
      const int ww = sp + (k % 3) - 1;
      const bool valid = (hh >= 0) & (hh < 64) & (ww >= 0) & (ww < 64);
      r = valid ? *(const u16x8*)(xtb + (((hh << 6) + ww) << 8) + (cc << 6) + sc0)
                : u16x8{};
    };
    auto PMFMA = [&](int it, int buf) {
      const int k = it >> 2, cc = it & 3;
#pragma unroll
      for (int kk = 0; kk < 2; ++kk) {
        const int prow = (nf << 4) + l16;
        const int gi = (kk << 2) | lh;
        bf16x8 bfrag = *(const bf16x8*)&S[buf][(prow << 6) + (((gi ^ (prow & 7)) & 7) << 3)];
        const __bf16* ap =
            womp + ((((k << 5) + (cc << 3) + (kk << 2) + lh) << 5) + (mf << 4) + l16) * 8;
        bf16x8 af = *(const bf16x8*)ap;
        if (kk == 0)
          oacc0 = __builtin_amdgcn_mfma_f32_16x16x32_bf16(af, bfrag, oacc0, 0, 0, 0);
        else
          oacc1 = __builtin_amdgcn_mfma_f32_16x16x32_bf16(af, bfrag, oacc1, 0, 0, 0);
      }
    };

    u16x8 p0, p1;
    PLOAD(0, p0);
    PLOAD(1, p1);
    *(u16x8*)&S[0][wofs] = p0;
    *(u16x8*)&S[1][wofs] = p1;
    __syncthreads();
    for (int p = 0; p < 18; ++p) {
      const int base = (p & 1) << 1;  // bufs staged last period: {base, base|1}
      const int nb = base ^ 2;        // bufs to stage this period
      if (p < 17) {
        PLOAD((p << 1) + 2, p0);
        PLOAD((p << 1) + 3, p1);
      }
      PMFMA(p << 1, base);
      PMFMA((p << 1) + 1, base | 1);
      if (p < 17) {
        *(u16x8*)&S[nb][wofs] = p0;
        *(u16x8*)&S[nb | 1][wofs] = p1;
      }
      __syncthreads();
    }

    f32x4 oacc = oacc0 + oacc1;
    const int px = (nf << 4) + l16;
#pragma unroll
    for (int r = 0; r < 4; ++r) {
      int row = (mf << 4) + (lh << 2) + r;
      if (row < 18) {
        offm[row][px] = oacc[r] + b_off[row];
      } else if (row < 27) {
        float v = oacc[r] + b_msk[row - 18];
        offm[row][px] = 1.f / (1.f + expf(-v));
      }
    }
    __syncthreads();
  }

  // ---- Precompute per-(tap,px) interp weights + clamped corner offsets ----
  for (int i = t; i < 576; i += 512) {
    int k = i >> 6, p = i & 63;
    float dy = offm[(k << 1)][p], dx = offm[(k << 1) + 1][p], mk = offm[18 + k][p];
    float ys = (float)(h + k / 3 - 1) + dy;
    float xs = (float)(p + k % 3 - 1) + dx;
    float y0f = floorf(ys), x0f = floorf(xs);
    int iy0 = (int)y0f, ix0 = (int)x0f;
    float wy1 = ys - y0f, wx1 = xs - x0f;
    float wy0 = 1.f - wy1, wx0 = 1.f - wx1;
    float w00 = wy0 * wx0 * mk, w01 = wy0 * wx1 * mk;
    float w10 = wy1 * wx0 * mk, w11 = wy1 * wx1 * mk;
    if (iy0 < 0 || iy0 > 63) { w00 = 0.f; w01 = 0.f; }
    if (iy0 < -1 || iy0 > 62) { w10 = 0.f; w11 = 0.f; }
    if (ix0 < 0 || ix0 > 63) { w00 = 0.f; w10 = 0.f; }
    if (ix0 < -1 || ix0 > 62) { w01 = 0.f; w11 = 0.f; }
    const int cy0 = min(max(iy0, 0), 63), cy1 = min(max(iy0 + 1, 0), 63);
    const int cx0 = min(max(ix0, 0), 63), cx1 = min(max(ix0 + 1, 0), 63);
    samp[k][p][0] = w00; samp[k][p][1] = w01;
    samp[k][p][2] = w10; samp[k][p][3] = w11;
    samp[k][p][4] = __builtin_bit_cast(float, (((cy0 << 6) + cx0) << 8));
    samp[k][p][5] = __builtin_bit_cast(float, (((cy0 << 6) + cx1) << 8));
    samp[k][p][6] = __builtin_bit_cast(float, (((cy1 << 6) + cx0) << 8));
    samp[k][p][7] = __builtin_bit_cast(float, (((cy1 << 6) + cx1) << 8));
  }
  __syncthreads();

  // ---- Main deformable GEMM (unchanged from v13/v14) ----
  f32x4 acc[2][4] = {};

  auto GATHER = [&](int it, u16x8* r, f32x4& w4) {
    const int k = it >> 2, cc = it & 3;
    w4 = *(const f32x4*)&samp[k][sp][0];
    i32x4 o4 = __builtin_bit_cast(i32x4, *(const f32x4*)&samp[k][sp][4]);
    const int c0 = (cc << 6) + sc0;
    r[0] = *(const u16x8*)(xtb + o4.x + c0);
    r[1] = *(const u16x8*)(xtb + o4.y + c0);
    r[2] = *(const u16x8*)(xtb + o4.z + c0);
    r[3] = *(const u16x8*)(xtb + o4.w + c0);
  };

  auto STEP = [&](int it, const u16x8* r, const f32x4& w4, int buf) {
    u16x8 sv;
    const unsigned* u0 = (const unsigned*)&r[0];
    const unsigned* u1 = (const unsigned*)&r[1];
    const unsigned* u2 = (const unsigned*)&r[2];
    const unsigned* u3 = (const unsigned*)&r[3];
#pragma unroll
    for (int j = 0; j < 4; ++j) {
      f32x2 a{blo(u0[j]), bhi(u0[j])};
      f32x2 b{blo(u1[j]), bhi(u1[j])};
      f32x2 c{blo(u2[j]), bhi(u2[j])};
      f32x2 d{blo(u3[j]), bhi(u3[j])};
      f32x2 s = a * w4.x;
      s += b * w4.y;
      s += c * w4.z;
      s += d * w4.w;
      sv[2 * j]     = f2b(s.x);
      sv[2 * j + 1] = f2b(s.y);
    }
    *(u16x8*)&S[buf][wofs] = sv;
    __syncthreads();
    const int k = it >> 2, cc = it & 3;
#pragma unroll
    for (int kk = 0; kk < 2; ++kk) {
      bf16x8 bfr[4];
#pragma unroll
      for (int nf = 0; nf < 4; ++nf) {
        const int prow = (nf << 4) + l16;
        const int gi = (kk << 2) | lh;
        bfr[nf] = *(const bf16x8*)&S[buf][(prow << 6) + (((gi ^ (prow & 7)) & 7) << 3)];
      }
#pragma unroll
      for (int mf = 0; mf < 2; ++mf) {
        const int orow = (wv << 5) + (mf << 4) + l16;
        const __bf16* ap = wp + ((((k << 5) + (cc << 3) + (kk << 2) + lh) << 8) + orow) * 8;
        bf16x8 af = *(const bf16x8*)ap;
#pragma unroll
        for (int nf = 0; nf < 4; ++nf)
          acc[mf][nf] = __builtin_amdgcn_mfma_f32_16x16x32_bf16(af, bfr[nf], acc[mf][nf], 0, 0, 0);
      }
    }
  };

  u16x8 rA[4], rB[4];
  f32x4 wA, wB;
  GATHER(0, rA, wA);
  for (int it = 0; it < 36; it += 2) {
    GATHER(it + 1, rB, wB);
    STEP(it, rA, wA, 0);
    if (it + 2 < 36) GATHER(it + 2, rA, wA);
    STEP(it + 1, rB, wB, 1);
  }

#pragma unroll
  for (int mf = 0; mf < 2; ++mf) {
    const int o = (wv << 5) + (mf << 4) + (lh << 2);
    f32x4 bv = *(const f32x4*)(bias + o);
#pragma unroll
    for (int nf = 0; nf < 4; ++nf) {
      const int p = (nf << 4) + l16;
      const int hw = (h << 6) + p;
#pragma unroll
      for (int r = 0; r < 4; ++r)
        out[(((bi << 8) + o + r) << 12) + hw] = acc[mf][nf][r] + bv[r];
    }
  }
}

extern "C" void kernel_launch(void* const* d_in, const int* in_sizes, int n_in,
                              void* d_out, int out_size, void* d_ws, size_t ws_size,
                              hipStream_t stream) {
  (void)in_sizes; (void)n_in; (void)out_size; (void)ws_size;
  const float* x        = (const float*)d_in[0];
  const float* w_offset = (const float*)d_in[1];
  const float* b_offset = (const float*)d_in[2];
  const float* w_mask   = (const float*)d_in[3];
  const float* b_mask   = (const float*)d_in[4];
  const float* weight   = (const float*)d_in[5];
  const float* bias     = (const float*)d_in[6];
  float* out = (float*)d_out;

  char* ws = (char*)d_ws;
  unsigned short* xt = (unsigned short*)(ws);
  __bf16* Wpack  = (__bf16*)(ws + 16777216);
  __bf16* Womp   = (__bf16*)(ws + 17956864);

  prep<<<4640, 256, 0, stream>>>(x, xt, weight, w_offset, w_mask, Wpack, Womp);
  deform_fused<<<512, 512, 0, stream>>>(xt, Wpack, Womp, b_offset, b_mask, bias, out);
}